// Round 11
// baseline (630.605 us; speedup 1.0000x reference)
//
#include <hip/hip_runtime.h>

typedef int v4i __attribute__((ext_vector_type(4)));

static constexpr int K_DIM = 4096;
static constexpr int BM = 128, BN = 128, BK = 64;

// ---------------- per-token dynamic quantization ----------------
__global__ __launch_bounds__(256) void quant_kernel(const float* __restrict__ x,
                                                    signed char* __restrict__ xq,
                                                    float* __restrict__ xs) {
    const int token = blockIdx.x;
    const float4* row = (const float4*)(x + (size_t)token * K_DIM);
    const int t = threadIdx.x;
    float4 v[4];
    float m = 0.f;
#pragma unroll
    for (int i = 0; i < 4; ++i) {
        v[i] = row[t * 4 + i];
        m = fmaxf(m, fabsf(v[i].x));
        m = fmaxf(m, fabsf(v[i].y));
        m = fmaxf(m, fabsf(v[i].z));
        m = fmaxf(m, fabsf(v[i].w));
    }
#pragma unroll
    for (int d = 32; d > 0; d >>= 1) m = fmaxf(m, __shfl_xor(m, d));
    __shared__ float red[4];
    if ((t & 63) == 0) red[t >> 6] = m;
    __syncthreads();
    const float am = fmaxf(fmaxf(red[0], red[1]), fmaxf(red[2], red[3]));
    const float s = fmaxf(am, 1e-8f) * (1.0f / 127.0f);
    const float inv = 127.0f / fmaxf(am, 1e-8f);

    int pk[4];
#pragma unroll
    for (int i = 0; i < 4; ++i) {
        int q0 = (int)fminf(127.f, fmaxf(-127.f, rintf(v[i].x * inv)));
        int q1 = (int)fminf(127.f, fmaxf(-127.f, rintf(v[i].y * inv)));
        int q2 = (int)fminf(127.f, fmaxf(-127.f, rintf(v[i].z * inv)));
        int q3 = (int)fminf(127.f, fmaxf(-127.f, rintf(v[i].w * inv)));
        pk[i] = (q0 & 255) | ((q1 & 255) << 8) | ((q2 & 255) << 16) | (q3 << 24);
    }
    ((int4*)(xq + (size_t)token * K_DIM))[t] = make_int4(pk[0], pk[1], pk[2], pk[3]);
    if (t == 0) xs[token] = s;
}

// ---------------- weight repack: int32 -> packed int8 ----------------
__global__ __launch_bounds__(256) void repack_kernel(const int* __restrict__ w32,
                                                     int4* __restrict__ w8,
                                                     int n16) {
    const int idx = blockIdx.x * 256 + threadIdx.x;
    if (idx >= n16) return;
    const int4* src = (const int4*)w32 + (size_t)idx * 4;
    int4 a = src[0], b = src[1], c = src[2], d = src[3];
    int p0 = (a.x & 255) | ((a.y & 255) << 8) | ((a.z & 255) << 16) | (a.w << 24);
    int p1 = (b.x & 255) | ((b.y & 255) << 8) | ((b.z & 255) << 16) | (b.w << 24);
    int p2 = (c.x & 255) | ((c.y & 255) << 8) | ((c.z & 255) << 16) | (c.w << 24);
    int p3 = (d.x & 255) | ((d.y & 255) << 8) | ((d.z & 255) << 16) | (d.w << 24);
    w8[idx] = make_int4(p0, p1, p2, p3);
}

// ---- int8 MFMA GEMM: 128x128 blocks, 256 thr (4 waves 2x2), wave 64x64,
// ---- BK=64 packed 128-B LDS rows (silicon-verified zero-conflict layout),
// ---- 2-buf 32 KB LDS -> 4-5 blocks/CU, one barrier per K-tile ----
__global__ __launch_bounds__(256, 4) void gemm_kernel(const signed char* __restrict__ xq,
                                                      const signed char* __restrict__ w8,
                                                      const float* __restrict__ xs,
                                                      const float* __restrict__ scale,
                                                      const float* __restrict__ bias,
                                                      float* __restrict__ out,
                                                      int N) {
    __shared__ __align__(16) signed char sA[2 * 8192];   // 2 bufs x 8 KB (64 rows x 128 B)
    __shared__ __align__(16) signed char sB[2 * 8192];

    const int tid = threadIdx.x;
    const int lane = tid & 63;
    const int wid = tid >> 6;          // 4 waves: 2(M) x 2(N)
    const int wm = wid >> 1;
    const int wn = wid & 1;

    // T1: XCD-aware bijective swizzle (grid = 86 x 64 = 5504, divisible by 8)
    const int nwg = gridDim.x * gridDim.y;
    int flat = blockIdx.y * gridDim.x + blockIdx.x;
    if ((nwg & 7) == 0) flat = (flat & 7) * (nwg >> 3) + (flat >> 3);
    const int by = flat % gridDim.y;          // M fast within chunk -> B panel L2-resident
    const int bx = flat / gridDim.y;
    const int m0 = by * BM;
    const int n0 = bx * BN;

    v4i acc[4][4];
    const v4i vzero = {0, 0, 0, 0};
#pragma unroll
    for (int i = 0; i < 4; ++i)
#pragma unroll
        for (int j = 0; j < 4; ++j) acc[i][j] = vzero;

    // ---- staging sources (verified involution; LDS dest linear) ----
    // 128 matrix rows packed as 64 LDS rows x 128 B: LDS row r slot s holds
    // matrix row r + (s>>2)*64, k-quarter s&3; phys slot = s ^ (r&7).
    const int srow = tid >> 3;                       // 0..31 (issue adds +32)
    const int s = (tid & 7) ^ (srow & 7);            // (srow+32)&7 == srow&7
    const signed char* srcA = xq + ((size_t)m0 + srow + (s >> 2) * 64) * K_DIM + (s & 3) * 16;
    const signed char* srcB = w8 + ((size_t)n0 + srow + (s >> 2) * 64) * K_DIM + (s & 3) * 16;

    auto stage = [&](int bufoff, unsigned int kb) {   // 4 issues x 4 KB (256 thr x 16 B)
        __builtin_amdgcn_global_load_lds(
            (const __attribute__((address_space(1))) void*)(srcA + kb),
            (__attribute__((address_space(3))) void*)&sA[bufoff + wid * 1024], 16, 0, 0);
        __builtin_amdgcn_global_load_lds(
            (const __attribute__((address_space(1))) void*)(srcA + (size_t)32 * K_DIM + kb),
            (__attribute__((address_space(3))) void*)&sA[bufoff + 4096 + wid * 1024], 16, 0, 0);
        __builtin_amdgcn_global_load_lds(
            (const __attribute__((address_space(1))) void*)(srcB + kb),
            (__attribute__((address_space(3))) void*)&sB[bufoff + wid * 1024], 16, 0, 0);
        __builtin_amdgcn_global_load_lds(
            (const __attribute__((address_space(1))) void*)(srcB + (size_t)32 * K_DIM + kb),
            (__attribute__((address_space(3))) void*)&sB[bufoff + 4096 + wid * 1024], 16, 0, 0);
    };

    // ---- read-side per-lane constants (verified zero-conflict pattern) ----
    const int colA = ((wm * 4 + (lane >> 4)) ^ (lane & 7)) << 4;   // wm selects packed half
    const int colB = ((wn * 4 + (lane >> 4)) ^ (lane & 7)) << 4;
    const int rowA = (lane & 15) * 128;                            // + mi*2048
    const int rowB = (lane & 15) * 128;                            // + ni*2048

    // body: [stage next tile into other buf] -> read frags -> MFMA -> vmcnt(0) -> barrier
#define BODY(RB, SB, DOSTAGE, KB, LASTWAIT)                                    \
    {                                                                          \
        if (DOSTAGE) stage((SB), (KB));                                        \
        v4i a_[4], b_[4];                                                      \
        _Pragma("unroll") for (int mi = 0; mi < 4; ++mi)                       \
            a_[mi] = *(const v4i*)&sA[(RB) + rowA + mi * 2048 + colA];         \
        _Pragma("unroll") for (int ni = 0; ni < 4; ++ni)                       \
            b_[ni] = *(const v4i*)&sB[(RB) + rowB + ni * 2048 + colB];         \
        asm volatile("s_waitcnt lgkmcnt(0)" ::: "memory");                     \
        __builtin_amdgcn_s_setprio(1);                                         \
        _Pragma("unroll") for (int mi = 0; mi < 4; ++mi)                       \
            _Pragma("unroll") for (int ni = 0; ni < 4; ++ni)                   \
                acc[mi][ni] = __builtin_amdgcn_mfma_i32_16x16x64_i8(           \
                    a_[mi], b_[ni], acc[mi][ni], 0, 0, 0);                     \
        __builtin_amdgcn_s_setprio(0);                                         \
        if (LASTWAIT) { asm volatile("s_waitcnt vmcnt(0)" ::: "memory"); }     \
        __builtin_amdgcn_s_barrier();                                          \
    }

    // ---- prologue: stage tile 0 into buf 0 ----
    stage(0, 0);
    asm volatile("s_waitcnt vmcnt(0)" ::: "memory");
    __builtin_amdgcn_s_barrier();

    // ---- main loop: bodies 0..61 (2-unrolled, static buf offsets) ----
    unsigned int kb = BK;
    for (int kt = 0; kt < 62; kt += 2) {
        BODY(0,    8192, 1, kb,      1);   // even: read buf0, stage t+1 -> buf1
        BODY(8192, 0,    1, kb + BK, 1);   // odd:  read buf1, stage t+2 -> buf0
        kb += 2 * BK;
    }
    // ---- tail: body 62 (stage 63 -> buf1), body 63 (pure) ----
    BODY(0,    8192, 1, (unsigned int)(63 * BK), 1);
    BODY(8192, 0,    0, 0u,                      0);
#undef BODY

    // ---- output epilogue: D reg r of lane l -> row (l>>4)*4+r, col l&15 per frag
    const int mrow0 = m0 + wm * 64 + ((lane >> 4) << 2);
    const int ncol0 = n0 + wn * 64 + (lane & 15);
    float xsv[4][4];
#pragma unroll
    for (int mi = 0; mi < 4; ++mi)
#pragma unroll
        for (int r = 0; r < 4; ++r) xsv[mi][r] = xs[mrow0 + mi * 16 + r];

#pragma unroll
    for (int ni = 0; ni < 4; ++ni) {
        const int n = ncol0 + ni * 16;
        const float sc = scale[n];
        const float bs = bias[n];
#pragma unroll
        for (int mi = 0; mi < 4; ++mi) {
#pragma unroll
            for (int r = 0; r < 4; ++r) {
                const int m = mrow0 + mi * 16 + r;
                out[(size_t)m * N + n] = (float)acc[mi][ni][r] * xsv[mi][r] * sc + bs;
            }
        }
    }
}

extern "C" void kernel_launch(void* const* d_in, const int* in_sizes, int n_in,
                              void* d_out, int out_size, void* d_ws, size_t ws_size,
                              hipStream_t stream) {
    const float* x     = (const float*)d_in[0];
    const int*   w32   = (const int*)d_in[1];
    const float* scale = (const float*)d_in[2];
    const float* bias  = (const float*)d_in[3];
    float* out = (float*)d_out;

    const int M = in_sizes[0] / K_DIM;   // 8192
    const int N = in_sizes[2];           // 11008

    char* ws = (char*)d_ws;
    signed char* xq = (signed char*)ws;                                  // M*K
    float* xs = (float*)(ws + (size_t)M * K_DIM);                        // M floats
    signed char* w8 = (signed char*)(ws + (size_t)M * K_DIM + (size_t)M * sizeof(float));  // N*K

    quant_kernel<<<M, 256, 0, stream>>>(x, xq, xs);

    const int n16 = (N * K_DIM) / 16;
    repack_kernel<<<(n16 + 255) / 256, 256, 0, stream>>>(w32, (int4*)w8, n16);

    gemm_kernel<<<dim3(N / BN, M / BM), 256, 0, stream>>>(xq, w8, xs, scale, bias, out, N);
}

// Round 12
// 626.628 us; speedup vs baseline: 1.0063x; 1.0063x over previous
//
#include <hip/hip_runtime.h>

typedef int v4i __attribute__((ext_vector_type(4)));

static constexpr int K_DIM = 4096;
static constexpr int BM = 128, BN = 128, BK = 64;

// ---------------- per-token dynamic quantization ----------------
__global__ __launch_bounds__(256) void quant_kernel(const float* __restrict__ x,
                                                    signed char* __restrict__ xq,
                                                    float* __restrict__ xs) {
    const int token = blockIdx.x;
    const float4* row = (const float4*)(x + (size_t)token * K_DIM);
    const int t = threadIdx.x;
    float4 v[4];
    float m = 0.f;
#pragma unroll
    for (int i = 0; i < 4; ++i) {
        v[i] = row[t * 4 + i];
        m = fmaxf(m, fabsf(v[i].x));
        m = fmaxf(m, fabsf(v[i].y));
        m = fmaxf(m, fabsf(v[i].z));
        m = fmaxf(m, fabsf(v[i].w));
    }
#pragma unroll
    for (int d = 32; d > 0; d >>= 1) m = fmaxf(m, __shfl_xor(m, d));
    __shared__ float red[4];
    if ((t & 63) == 0) red[t >> 6] = m;
    __syncthreads();
    const float am = fmaxf(fmaxf(red[0], red[1]), fmaxf(red[2], red[3]));
    const float s = fmaxf(am, 1e-8f) * (1.0f / 127.0f);
    const float inv = 127.0f / fmaxf(am, 1e-8f);

    int pk[4];
#pragma unroll
    for (int i = 0; i < 4; ++i) {
        int q0 = (int)fminf(127.f, fmaxf(-127.f, rintf(v[i].x * inv)));
        int q1 = (int)fminf(127.f, fmaxf(-127.f, rintf(v[i].y * inv)));
        int q2 = (int)fminf(127.f, fmaxf(-127.f, rintf(v[i].z * inv)));
        int q3 = (int)fminf(127.f, fmaxf(-127.f, rintf(v[i].w * inv)));
        pk[i] = (q0 & 255) | ((q1 & 255) << 8) | ((q2 & 255) << 16) | (q3 << 24);
    }
    ((int4*)(xq + (size_t)token * K_DIM))[t] = make_int4(pk[0], pk[1], pk[2], pk[3]);
    if (t == 0) xs[token] = s;
}

// ---------------- weight repack: int32 -> packed int8 ----------------
__global__ __launch_bounds__(256) void repack_kernel(const int* __restrict__ w32,
                                                     int4* __restrict__ w8,
                                                     int n16) {
    const int idx = blockIdx.x * 256 + threadIdx.x;
    if (idx >= n16) return;
    const int4* src = (const int4*)w32 + (size_t)idx * 4;
    int4 a = src[0], b = src[1], c = src[2], d = src[3];
    int p0 = (a.x & 255) | ((a.y & 255) << 8) | ((a.z & 255) << 16) | (a.w << 24);
    int p1 = (b.x & 255) | ((b.y & 255) << 8) | ((b.z & 255) << 16) | (b.w << 24);
    int p2 = (c.x & 255) | ((c.y & 255) << 8) | ((c.z & 255) << 16) | (c.w << 24);
    int p3 = (d.x & 255) | ((d.y & 255) << 8) | ((d.z & 255) << 16) | (d.w << 24);
    w8[idx] = make_int4(p0, p1, p2, p3);
}

// ---- int8 MFMA GEMM: 128x128 blocks, 256 thr (4 waves 2x2), wave 64x64,
// ---- BK=64 packed 128-B LDS rows (silicon-verified zero-conflict layout),
// ---- 3-buf 48 KB LDS -> 3 blocks/CU (phase-diverse barrier groups),
// ---- counted vmcnt(8) with distance-2 verify (never drains mid-loop) ----
__global__ __launch_bounds__(256, 4) void gemm_kernel(const signed char* __restrict__ xq,
                                                      const signed char* __restrict__ w8,
                                                      const float* __restrict__ xs,
                                                      const float* __restrict__ scale,
                                                      const float* __restrict__ bias,
                                                      float* __restrict__ out,
                                                      int N) {
    __shared__ __align__(16) signed char sA[3 * 8192];   // 3 bufs x 8 KB (64 rows x 128 B)
    __shared__ __align__(16) signed char sB[3 * 8192];

    const int tid = threadIdx.x;
    const int lane = tid & 63;
    const int wid = tid >> 6;          // 4 waves: 2(M) x 2(N)
    const int wm = wid >> 1;
    const int wn = wid & 1;

    // T1: XCD-aware bijective swizzle (grid = 86 x 64 = 5504, divisible by 8)
    const int nwg = gridDim.x * gridDim.y;
    int flat = blockIdx.y * gridDim.x + blockIdx.x;
    if ((nwg & 7) == 0) flat = (flat & 7) * (nwg >> 3) + (flat >> 3);
    const int by = flat % gridDim.y;          // M fast within chunk -> B panel L2-resident
    const int bx = flat / gridDim.y;
    const int m0 = by * BM;
    const int n0 = bx * BN;

    v4i acc[4][4];
    const v4i vzero = {0, 0, 0, 0};
#pragma unroll
    for (int i = 0; i < 4; ++i)
#pragma unroll
        for (int j = 0; j < 4; ++j) acc[i][j] = vzero;

    // ---- staging sources (verified involution; LDS dest linear) ----
    // 128 matrix rows packed as 64 LDS rows x 128 B: LDS row r slot s holds
    // matrix row r + (s>>2)*64, k-quarter s&3; phys slot = s ^ (r&7).
    const int srow = tid >> 3;                       // 0..31 (second issue adds +32)
    const int s = (tid & 7) ^ (srow & 7);            // (srow+32)&7 == srow&7
    const signed char* srcA = xq + ((size_t)m0 + srow + (s >> 2) * 64) * K_DIM + (s & 3) * 16;
    const signed char* srcB = w8 + ((size_t)n0 + srow + (s >> 2) * 64) * K_DIM + (s & 3) * 16;

    auto stage = [&](int bufoff, unsigned int kb) {   // 4 issues x 4 KB (256 thr x 16 B)
        __builtin_amdgcn_global_load_lds(
            (const __attribute__((address_space(1))) void*)(srcA + kb),
            (__attribute__((address_space(3))) void*)&sA[bufoff + wid * 1024], 16, 0, 0);
        __builtin_amdgcn_global_load_lds(
            (const __attribute__((address_space(1))) void*)(srcA + (size_t)32 * K_DIM + kb),
            (__attribute__((address_space(3))) void*)&sA[bufoff + 4096 + wid * 1024], 16, 0, 0);
        __builtin_amdgcn_global_load_lds(
            (const __attribute__((address_space(1))) void*)(srcB + kb),
            (__attribute__((address_space(3))) void*)&sB[bufoff + wid * 1024], 16, 0, 0);
        __builtin_amdgcn_global_load_lds(
            (const __attribute__((address_space(1))) void*)(srcB + (size_t)32 * K_DIM + kb),
            (__attribute__((address_space(3))) void*)&sB[bufoff + 4096 + wid * 1024], 16, 0, 0);
    };

    // ---- read-side per-lane constants (verified zero-conflict pattern) ----
    const int colA = ((wm * 4 + (lane >> 4)) ^ (lane & 7)) << 4;   // wm selects packed half
    const int colB = ((wn * 4 + (lane >> 4)) ^ (lane & 7)) << 4;
    const int rowA = (lane & 15) * 128;                            // + mi*2048
    const int rowB = (lane & 15) * 128;                            // + ni*2048

    // body: read frags -> MFMA -> barrier -> [stage t+3 into just-read buf] ->
    // counted vmcnt (verifies tile t+1, staged 2 bodies ago) -> barrier
#define BODY(RB, DOSTAGE, KB, VMSTR)                                           \
    {                                                                          \
        v4i a_[4], b_[4];                                                      \
        _Pragma("unroll") for (int mi = 0; mi < 4; ++mi)                       \
            a_[mi] = *(const v4i*)&sA[(RB) + rowA + mi * 2048 + colA];         \
        _Pragma("unroll") for (int ni = 0; ni < 4; ++ni)                       \
            b_[ni] = *(const v4i*)&sB[(RB) + rowB + ni * 2048 + colB];         \
        asm volatile("s_waitcnt lgkmcnt(0)" ::: "memory");                     \
        __builtin_amdgcn_s_setprio(1);                                         \
        _Pragma("unroll") for (int mi = 0; mi < 4; ++mi)                       \
            _Pragma("unroll") for (int ni = 0; ni < 4; ++ni)                   \
                acc[mi][ni] = __builtin_amdgcn_mfma_i32_16x16x64_i8(           \
                    a_[mi], b_[ni], acc[mi][ni], 0, 0, 0);                     \
        __builtin_amdgcn_s_setprio(0);                                         \
        __builtin_amdgcn_s_barrier();                                          \
        if (DOSTAGE) stage((RB), (KB));                                        \
        asm volatile("s_waitcnt vmcnt(" VMSTR ")" ::: "memory");               \
        __builtin_amdgcn_s_barrier();                                          \
    }

    // ---- prologue: stage tiles 0,1,2 into bufs 0,1,2; publish tile 0 ----
    stage(0, 0);
    stage(8192, BK);
    stage(16384, 2 * BK);
    asm volatile("s_waitcnt vmcnt(8)" ::: "memory");   // tile 0 (4 oldest issues) landed
    __builtin_amdgcn_s_barrier();

    // ---- main loop: bodies 0..59 (20 x 3, static buf offsets) ----
    unsigned int kb = 3 * BK;   // byte offset of tile staged this body
    for (int it = 0; it < 20; ++it) {
        BODY(0,     1, kb,          "8");   // body 3it+0: reads buf0, stages t+3
        BODY(8192,  1, kb + BK,     "8");   // body 3it+1: reads buf1
        BODY(16384, 1, kb + 2 * BK, "8");   // body 3it+2: reads buf2
        kb += 3 * BK;
    }

    // ---- tail: body 60 stages tile 63; waits 8/4/0; body 63 pure ----
    BODY(0,     1, (unsigned int)(63 * BK), "8");   // body 60
    BODY(8192,  0, 0u,                      "4");   // body 61: verifies tile 62
    BODY(16384, 0, 0u,                      "0");   // body 62: verifies tile 63
    {   // body 63: reads buf0 (tile 63), MFMA only
        v4i a_[4], b_[4];
#pragma unroll
        for (int mi = 0; mi < 4; ++mi)
            a_[mi] = *(const v4i*)&sA[0 + rowA + mi * 2048 + colA];
#pragma unroll
        for (int ni = 0; ni < 4; ++ni)
            b_[ni] = *(const v4i*)&sB[0 + rowB + ni * 2048 + colB];
        asm volatile("s_waitcnt lgkmcnt(0)" ::: "memory");
        __builtin_amdgcn_s_setprio(1);
#pragma unroll
        for (int mi = 0; mi < 4; ++mi)
#pragma unroll
            for (int ni = 0; ni < 4; ++ni)
                acc[mi][ni] = __builtin_amdgcn_mfma_i32_16x16x64_i8(
                    a_[mi], b_[ni], acc[mi][ni], 0, 0, 0);
        __builtin_amdgcn_s_setprio(0);
    }
#undef BODY

    // ---- output epilogue: D reg r of lane l -> row (l>>4)*4+r, col l&15 per frag
    const int mrow0 = m0 + wm * 64 + ((lane >> 4) << 2);
    const int ncol0 = n0 + wn * 64 + (lane & 15);
    float xsv[4][4];
#pragma unroll
    for (int mi = 0; mi < 4; ++mi)
#pragma unroll
        for (int r = 0; r < 4; ++r) xsv[mi][r] = xs[mrow0 + mi * 16 + r];

#pragma unroll
    for (int ni = 0; ni < 4; ++ni) {
        const int n = ncol0 + ni * 16;
        const float sc = scale[n];
        const float bs = bias[n];
#pragma unroll
        for (int mi = 0; mi < 4; ++mi) {
#pragma unroll
            for (int r = 0; r < 4; ++r) {
                const int m = mrow0 + mi * 16 + r;
                out[(size_t)m * N + n] = (float)acc[mi][ni][r] * xsv[mi][r] * sc + bs;
            }
        }
    }
}

extern "C" void kernel_launch(void* const* d_in, const int* in_sizes, int n_in,
                              void* d_out, int out_size, void* d_ws, size_t ws_size,
                              hipStream_t stream) {
    const float* x     = (const float*)d_in[0];
    const int*   w32   = (const int*)d_in[1];
    const float* scale = (const float*)d_in[2];
    const float* bias  = (const float*)d_in[3];
    float* out = (float*)d_out;

    const int M = in_sizes[0] / K_DIM;   // 8192
    const int N = in_sizes[2];           // 11008

    char* ws = (char*)d_ws;
    signed char* xq = (signed char*)ws;                                  // M*K
    float* xs = (float*)(ws + (size_t)M * K_DIM);                        // M floats
    signed char* w8 = (signed char*)(ws + (size_t)M * K_DIM + (size_t)M * sizeof(float));  // N*K

    quant_kernel<<<M, 256, 0, stream>>>(x, xq, xs);

    const int n16 = (N * K_DIM) / 16;
    repack_kernel<<<(n16 + 255) / 256, 256, 0, stream>>>(w32, (int4*)w8, n16);

    gemm_kernel<<<dim3(N / BN, M / BM), 256, 0, stream>>>(xq, w8, xs, scale, bias, out, N);
}